// Round 1
// baseline (1017.814 us; speedup 1.0000x reference)
//
#include <hip/hip_runtime.h>
#include <cstdint>

#define CE_BATCH 4096
#define CE_VOCAB 50257

// Latency-bound fix: 8 float4 loads in flight per thread, 8 independent
// partial sums, deferred-max rescale (taken ~4x per thread total).
__global__ __launch_bounds__(256, 4) void ce_kernel(const float* __restrict__ pred,
                                                    const int* __restrict__ y,
                                                    float* __restrict__ out) {
    const int b = blockIdx.x;
    const float* __restrict__ row = pred + (size_t)b * CE_VOCAB;
    const int tid = threadIdx.x;

    // Deferred-max state: m is the running max; s0..s7 are partial sums of
    // exp(x - m). On a new record max we rescale all 8 sums (rare).
    float m = -INFINITY;
    float s0 = 0.0f, s1 = 0.0f, s2 = 0.0f, s3 = 0.0f;
    float s4 = 0.0f, s5 = 0.0f, s6 = 0.0f, s7 = 0.0f;

    // Rows are only 4B-aligned relative to each other (50257 % 4 == 1).
    // Peel scalar prefix so float4 region is 16B aligned.
    int lead = (int)(((16u - ((uintptr_t)row & 15u)) & 15u) >> 2);
    if (lead > CE_VOCAB) lead = CE_VOCAB;
    if (tid < lead) {
        m = row[tid];
        s0 = 1.0f;
    }

    const int nvec = (CE_VOCAB - lead) >> 2;  // number of float4s (~12563)
    const float4* __restrict__ vrow = (const float4*)(row + lead);

    int i = tid;
    // Main loop: 8 batched float4 loads (all issued before any use -> 8
    // outstanding global_load_dwordx4 per wave). Every lane executes >=1
    // iteration (nvec >= 12563 > tid + 1792), so m is finite afterwards.
    for (; i + 7 * 256 < nvec; i += 8 * 256) {
        float4 v0 = vrow[i];
        float4 v1 = vrow[i + 1 * 256];
        float4 v2 = vrow[i + 2 * 256];
        float4 v3 = vrow[i + 3 * 256];
        float4 v4 = vrow[i + 4 * 256];
        float4 v5 = vrow[i + 5 * 256];
        float4 v6 = vrow[i + 6 * 256];
        float4 v7 = vrow[i + 7 * 256];

        float m0 = fmaxf(fmaxf(v0.x, v0.y), fmaxf(v0.z, v0.w));
        float m1 = fmaxf(fmaxf(v1.x, v1.y), fmaxf(v1.z, v1.w));
        float m2 = fmaxf(fmaxf(v2.x, v2.y), fmaxf(v2.z, v2.w));
        float m3 = fmaxf(fmaxf(v3.x, v3.y), fmaxf(v3.z, v3.w));
        float m4 = fmaxf(fmaxf(v4.x, v4.y), fmaxf(v4.z, v4.w));
        float m5 = fmaxf(fmaxf(v5.x, v5.y), fmaxf(v5.z, v5.w));
        float m6 = fmaxf(fmaxf(v6.x, v6.y), fmaxf(v6.z, v6.w));
        float m7 = fmaxf(fmaxf(v7.x, v7.y), fmaxf(v7.z, v7.w));
        float g = fmaxf(fmaxf(fmaxf(m0, m1), fmaxf(m2, m3)),
                        fmaxf(fmaxf(m4, m5), fmaxf(m6, m7)));

        if (g > m) {  // record max: rescale (rare; exp(-inf)=0 handles init)
            float r = __expf(m - g);
            s0 *= r; s1 *= r; s2 *= r; s3 *= r;
            s4 *= r; s5 *= r; s6 *= r; s7 *= r;
            m = g;
        }

        // 8 independent accumulation chains -> full ILP, no serial exp chain.
        s0 += (__expf(v0.x - m) + __expf(v0.y - m)) + (__expf(v0.z - m) + __expf(v0.w - m));
        s1 += (__expf(v1.x - m) + __expf(v1.y - m)) + (__expf(v1.z - m) + __expf(v1.w - m));
        s2 += (__expf(v2.x - m) + __expf(v2.y - m)) + (__expf(v2.z - m) + __expf(v2.w - m));
        s3 += (__expf(v3.x - m) + __expf(v3.y - m)) + (__expf(v3.z - m) + __expf(v3.w - m));
        s4 += (__expf(v4.x - m) + __expf(v4.y - m)) + (__expf(v4.z - m) + __expf(v4.w - m));
        s5 += (__expf(v5.x - m) + __expf(v5.y - m)) + (__expf(v5.z - m) + __expf(v5.w - m));
        s6 += (__expf(v6.x - m) + __expf(v6.y - m)) + (__expf(v6.z - m) + __expf(v6.w - m));
        s7 += (__expf(v7.x - m) + __expf(v7.y - m)) + (__expf(v7.z - m) + __expf(v7.w - m));
    }

    // Remainder float4s (<= 1 per thread for this shape).
    for (; i < nvec; i += 256) {
        float4 v = vrow[i];
        float g = fmaxf(fmaxf(v.x, v.y), fmaxf(v.z, v.w));
        if (g > m) {
            float r = __expf(m - g);
            s0 *= r; s1 *= r; s2 *= r; s3 *= r;
            s4 *= r; s5 *= r; s6 *= r; s7 *= r;
            m = g;
        }
        s0 += (__expf(v.x - m) + __expf(v.y - m)) + (__expf(v.z - m) + __expf(v.w - m));
    }

    // Scalar tail (0..3 elements).
    int t = lead + (nvec << 2) + tid;
    if (t < CE_VOCAB) {
        float x = row[t];
        if (x > m) {
            float r = __expf(m - x);
            s0 *= r; s1 *= r; s2 *= r; s3 *= r;
            s4 *= r; s5 *= r; s6 *= r; s7 *= r;
            m = x;
        }
        s0 += __expf(x - m);
    }

    float s = ((s0 + s1) + (s2 + s3)) + ((s4 + s5) + (s6 + s7));

    // Wave (64-lane) butterfly reduction of (m, s). All lanes have finite m
    // here (every lane processed >= 1 batched iteration), so no NaN from
    // (-inf) - (-inf).
    #pragma unroll
    for (int off = 1; off < 64; off <<= 1) {
        float om = __shfl_xor(m, off, 64);
        float os = __shfl_xor(s, off, 64);
        float nm = fmaxf(m, om);
        s = s * __expf(m - nm) + os * __expf(om - nm);
        m = nm;
    }

    __shared__ float sm[4];
    __shared__ float ss[4];
    const int wave = tid >> 6;
    if ((tid & 63) == 0) {
        sm[wave] = m;
        ss[wave] = s;
    }
    __syncthreads();

    if (tid == 0) {
        m = sm[0];
        s = ss[0];
        #pragma unroll
        for (int w = 1; w < 4; ++w) {
            float om = sm[w], os = ss[w];
            float nm = fmaxf(m, om);
            s = s * __expf(m - nm) + os * __expf(om - nm);
            m = nm;
        }
        float lse = m + __logf(s);
        float loss = lse - row[y[b]];
        atomicAdd(out, loss * (1.0f / CE_BATCH));
    }
}

extern "C" void kernel_launch(void* const* d_in, const int* in_sizes, int n_in,
                              void* d_out, int out_size, void* d_ws, size_t ws_size,
                              hipStream_t stream) {
    const float* pred = (const float*)d_in[0];
    const int* y = (const int*)d_in[1];
    float* out = (float*)d_out;

    // d_out is poisoned to 0xAA before every launch; zero it on-stream
    // (graph-capture safe, same pattern the harness itself uses).
    hipMemsetAsync(out, 0, sizeof(float), stream);

    ce_kernel<<<CE_BATCH, 256, 0, stream>>>(pred, y, out);
}

// Round 2
// 994.358 us; speedup vs baseline: 1.0236x; 1.0236x over previous
//
#include <hip/hip_runtime.h>
#include <cstdint>

#define CE_BATCH 4096
#define CE_VOCAB 50257

typedef float f32x4 __attribute__((ext_vector_type(4)));

// Round-2 theory: per-wave CONTIGUOUS streaming (no 4KB-strided wave streams),
// 8 waves/SIMD TLP (launch_bounds min-waves=8 -> VGPR cap 64), nontemporal
// loads (no L2/L3 allocation against the harness fill's dirty lines).
__global__ __launch_bounds__(256, 8) void ce_kernel(const float* __restrict__ pred,
                                                    const int* __restrict__ y,
                                                    float* __restrict__ out) {
    const int b = blockIdx.x;
    const float* __restrict__ row = pred + (size_t)b * CE_VOCAB;
    const int tid = threadIdx.x;
    const int wave = tid >> 6;
    const int lane = tid & 63;

    // Deferred-max state: m = running max, s0..s3 partial sums of exp(x-m).
    float m = -INFINITY;
    float s0 = 0.0f, s1 = 0.0f, s2 = 0.0f, s3 = 0.0f;

    // Rows are only 4B-aligned relative to each other (50257 % 4 == 1).
    // Peel scalar prefix so the float4 region is 16B aligned.
    int lead = (int)(((16u - ((uintptr_t)row & 15u)) & 15u) >> 2);
    if (lead > CE_VOCAB) lead = CE_VOCAB;
    if (tid < lead) {
        m = row[tid];
        s0 = 1.0f;
    }

    const int nvec = (CE_VOCAB - lead) >> 2;  // ~12563 float4s
    const f32x4* __restrict__ vrow = (const f32x4*)(row + lead);

    // Contiguous chunk per wave: wave w owns float4s [w*chunk, min(+chunk,nvec)).
    // Each wave-iteration reads 1KB contiguous; batched x4 = 4KB contiguous.
    const int chunk = (nvec + 3) >> 2;                 // ~3141
    const int wbeg = wave * chunk;
    const int wend0 = wbeg + chunk;
    const int wend = wend0 < nvec ? wend0 : nvec;

    int i = wbeg + lane;
    // Every lane executes >=1 batched iteration (chunk >= 3140 > 63+192),
    // so m is finite for all lanes afterwards (no -inf NaN in the reduce).
    for (; i + 3 * 64 < wend; i += 4 * 64) {
        f32x4 v0 = __builtin_nontemporal_load(vrow + i);
        f32x4 v1 = __builtin_nontemporal_load(vrow + i + 64);
        f32x4 v2 = __builtin_nontemporal_load(vrow + i + 128);
        f32x4 v3 = __builtin_nontemporal_load(vrow + i + 192);

        float m0 = fmaxf(fmaxf(v0.x, v0.y), fmaxf(v0.z, v0.w));
        float m1 = fmaxf(fmaxf(v1.x, v1.y), fmaxf(v1.z, v1.w));
        float m2 = fmaxf(fmaxf(v2.x, v2.y), fmaxf(v2.z, v2.w));
        float m3 = fmaxf(fmaxf(v3.x, v3.y), fmaxf(v3.z, v3.w));
        float g = fmaxf(fmaxf(m0, m1), fmaxf(m2, m3));

        if (g > m) {  // record max: rescale (rare)
            float r = __expf(m - g);
            s0 *= r; s1 *= r; s2 *= r; s3 *= r;
            m = g;
        }

        // 4 independent accumulation chains.
        s0 += (__expf(v0.x - m) + __expf(v0.y - m)) + (__expf(v0.z - m) + __expf(v0.w - m));
        s1 += (__expf(v1.x - m) + __expf(v1.y - m)) + (__expf(v1.z - m) + __expf(v1.w - m));
        s2 += (__expf(v2.x - m) + __expf(v2.y - m)) + (__expf(v2.z - m) + __expf(v2.w - m));
        s3 += (__expf(v3.x - m) + __expf(v3.y - m)) + (__expf(v3.z - m) + __expf(v3.w - m));
    }

    // Remainder float4s within this wave's chunk.
    for (; i < wend; i += 64) {
        f32x4 v = __builtin_nontemporal_load(vrow + i);
        float g = fmaxf(fmaxf(v.x, v.y), fmaxf(v.z, v.w));
        if (g > m) {
            float r = __expf(m - g);
            s0 *= r; s1 *= r; s2 *= r; s3 *= r;
            m = g;
        }
        s0 += (__expf(v.x - m) + __expf(v.y - m)) + (__expf(v.z - m) + __expf(v.w - m));
    }

    // Scalar tail (0..3 elements at row end).
    int t = lead + (nvec << 2) + tid;
    if (t < CE_VOCAB) {
        float x = row[t];
        if (x > m) {
            float r = __expf(m - x);
            s0 *= r; s1 *= r; s2 *= r; s3 *= r;
            m = x;
        }
        s0 += __expf(x - m);
    }

    float s = (s0 + s1) + (s2 + s3);

    // Wave (64-lane) butterfly reduction of (m, s).
    #pragma unroll
    for (int off = 1; off < 64; off <<= 1) {
        float om = __shfl_xor(m, off, 64);
        float os = __shfl_xor(s, off, 64);
        float nm = fmaxf(m, om);
        s = s * __expf(m - nm) + os * __expf(om - nm);
        m = nm;
    }

    __shared__ float sm[4];
    __shared__ float ss[4];
    if ((tid & 63) == 0) {
        sm[wave] = m;
        ss[wave] = s;
    }
    __syncthreads();

    if (tid == 0) {
        m = sm[0];
        s = ss[0];
        #pragma unroll
        for (int w = 1; w < 4; ++w) {
            float om = sm[w], os = ss[w];
            float nm = fmaxf(m, om);
            s = s * __expf(m - nm) + os * __expf(om - nm);
            m = nm;
        }
        float lse = m + __logf(s);
        float loss = lse - row[y[b]];
        atomicAdd(out, loss * (1.0f / CE_BATCH));
    }
}

extern "C" void kernel_launch(void* const* d_in, const int* in_sizes, int n_in,
                              void* d_out, int out_size, void* d_ws, size_t ws_size,
                              hipStream_t stream) {
    const float* pred = (const float*)d_in[0];
    const int* y = (const int*)d_in[1];
    float* out = (float*)d_out;

    // d_out is poisoned to 0xAA before every launch; zero it on-stream
    // (graph-capture safe, same pattern the harness itself uses).
    hipMemsetAsync(out, 0, sizeof(float), stream);

    ce_kernel<<<CE_BATCH, 256, 0, stream>>>(pred, y, out);
}